// Round 10
// baseline (28.827 us; speedup 1.0000x reference)
//
#include <hip/hip_runtime.h>
#include <math.h>

#define NBLK 2048
#define NTHR 256
#define NWAVE (NTHR / 64)
#define PER_THREAD 16  // float4s per thread in the fast path

typedef float f32x4 __attribute__((ext_vector_type(4)));

// Kernel 1: each block reduces a contiguous 64 KiB chunk (4096 float4).
// 4 independent accumulator streams; each wave iteration covers one
// contiguous 16 KiB window. Plain loads (L3-resident input: let the
// Infinity Cache serve replays — nt forfeited that).
__global__ __launch_bounds__(NTHR) void grt_partial_kernel(
    const float* __restrict__ x, float2* __restrict__ part, int n4) {
    const f32x4* __restrict__ x4 = reinterpret_cast<const f32x4*>(x);

    float s0 = 0.f, s1 = 0.f, s2 = 0.f, s3 = 0.f;
    float q0 = 0.f, q1 = 0.f, q2 = 0.f, q3 = 0.f;

    if (n4 == NBLK * NTHR * PER_THREAD) {
        // Fast path: exact static partition.
        const int base = blockIdx.x * (NTHR * PER_THREAD) + threadIdx.x;
        #pragma unroll
        for (int g = 0; g < PER_THREAD / 4; ++g) {
            f32x4 a = x4[base + (g * 4 + 0) * NTHR];
            f32x4 b = x4[base + (g * 4 + 1) * NTHR];
            f32x4 c = x4[base + (g * 4 + 2) * NTHR];
            f32x4 d = x4[base + (g * 4 + 3) * NTHR];
            s0 += a[0] + a[1] + a[2] + a[3];
            s1 += b[0] + b[1] + b[2] + b[3];
            s2 += c[0] + c[1] + c[2] + c[3];
            s3 += d[0] + d[1] + d[2] + d[3];
            q0 = fmaf(a[0], a[0], q0); q0 = fmaf(a[1], a[1], q0);
            q0 = fmaf(a[2], a[2], q0); q0 = fmaf(a[3], a[3], q0);
            q1 = fmaf(b[0], b[0], q1); q1 = fmaf(b[1], b[1], q1);
            q1 = fmaf(b[2], b[2], q1); q1 = fmaf(b[3], b[3], q1);
            q2 = fmaf(c[0], c[0], q2); q2 = fmaf(c[1], c[1], q2);
            q2 = fmaf(c[2], c[2], q2); q2 = fmaf(c[3], c[3], q2);
            q3 = fmaf(d[0], d[0], q3); q3 = fmaf(d[1], d[1], q3);
            q3 = fmaf(d[2], d[2], q3); q3 = fmaf(d[3], d[3], q3);
        }
    } else {
        // Generic grid-stride fallback.
        const int tid = blockIdx.x * NTHR + threadIdx.x;
        const int stride = NBLK * NTHR;
        for (int i = tid; i < n4; i += stride) {
            f32x4 a = x4[i];
            s0 += a[0] + a[1] + a[2] + a[3];
            q0 = fmaf(a[0], a[0], q0); q0 = fmaf(a[1], a[1], q0);
            q0 = fmaf(a[2], a[2], q0); q0 = fmaf(a[3], a[3], q0);
        }
    }
    float s = (s0 + s1) + (s2 + s3);
    float q = (q0 + q1) + (q2 + q3);

    #pragma unroll
    for (int off = 32; off > 0; off >>= 1) {
        s += __shfl_down(s, off, 64);
        q += __shfl_down(q, off, 64);
    }

    __shared__ float2 lds[NWAVE];
    const int lane = threadIdx.x & 63;
    const int wave = threadIdx.x >> 6;
    if (lane == 0) lds[wave] = make_float2(s, q);
    __syncthreads();

    if (threadIdx.x == 0) {
        float2 acc = lds[0];
        #pragma unroll
        for (int w = 1; w < NWAVE; ++w) {
            acc.x += lds[w].x;
            acc.y += lds[w].y;
        }
        part[blockIdx.x] = acc;
    }
}

// Kernel 2: single wave. Partials read as float4 (pairs of float2).
__global__ __launch_bounds__(64) void grt_final_kernel(
    const float4* __restrict__ part4,  // NBLK/2 float4
    const float* __restrict__ log_sw, const float* __restrict__ log_sz,
    const float* __restrict__ log_sx, float* __restrict__ out, float dn) {
    float s = 0.f, q = 0.f;
    #pragma unroll 4
    for (int i = threadIdx.x; i < NBLK / 2; i += 64) {
        float4 v = part4[i];
        s += v.x + v.z;
        q += v.y + v.w;
    }

    #pragma unroll
    for (int off = 32; off > 0; off >>= 1) {
        s += __shfl_down(s, off, 64);
        q += __shfl_down(q, off, 64);
    }

    if (threadIdx.x == 0) {
        double ss = (double)s, qq = (double)q;
        double n = (double)dn;
        double b = exp(2.0 * (double)log_sw[0]);
        double a = exp(2.0 * (double)log_sz[0]) + exp(2.0 * (double)log_sx[0]);
        double quad = qq / a - b * ss * ss / (a * (a + n * b));
        double logdet = (n - 1.0) * log(a) + log(a + n * b);
        const double LOG_2PI = 1.837877066409345483560659472811;
        out[0] = (float)(-0.5 * (n * LOG_2PI + logdet + quad));
    }
}

extern "C" void kernel_launch(void* const* d_in, const int* in_sizes, int n_in,
                              void* d_out, int out_size, void* d_ws, size_t ws_size,
                              hipStream_t stream) {
    const float* x      = (const float*)d_in[0];
    const float* log_sw = (const float*)d_in[1];
    const float* log_sz = (const float*)d_in[2];
    const float* log_sx = (const float*)d_in[3];
    float* out = (float*)d_out;
    int n = in_sizes[0];  // 33554432
    int n4 = n >> 2;

    float2* part = (float2*)d_ws;  // 2048 float2 = 16 KiB

    grt_partial_kernel<<<NBLK, NTHR, 0, stream>>>(x, part, n4);
    grt_final_kernel<<<1, 64, 0, stream>>>((const float4*)part, log_sw, log_sz,
                                           log_sx, out, (float)n);
}

// Round 11
// 26.727 us; speedup vs baseline: 1.0786x; 1.0786x over previous
//
#include <hip/hip_runtime.h>
#include <math.h>

#define NBLK 2048
#define NTHR 256
#define NWAVE (NTHR / 64)
#define PER_THREAD 16  // float4s per thread in the fast path

typedef float f32x4 __attribute__((ext_vector_type(4)));

// Kernel 1: each block reduces a contiguous 64 KiB chunk (4096 float4).
// 4 independent accumulator streams; each wave iteration covers one
// contiguous 16 KiB window. Non-temporal loads: measured A/B (r5=26.8 vs
// r10=28.8 µs) shows nt is worth ~2 µs — evict-first streaming beats
// L2/L3 retention for this 128 MiB one-pass read.
__global__ __launch_bounds__(NTHR) void grt_partial_kernel(
    const float* __restrict__ x, float2* __restrict__ part, int n4) {
    const f32x4* __restrict__ x4 = reinterpret_cast<const f32x4*>(x);

    float s0 = 0.f, s1 = 0.f, s2 = 0.f, s3 = 0.f;
    float q0 = 0.f, q1 = 0.f, q2 = 0.f, q3 = 0.f;

    if (n4 == NBLK * NTHR * PER_THREAD) {
        // Fast path: exact static partition.
        const int base = blockIdx.x * (NTHR * PER_THREAD) + threadIdx.x;
        #pragma unroll
        for (int g = 0; g < PER_THREAD / 4; ++g) {
            f32x4 a = __builtin_nontemporal_load(&x4[base + (g * 4 + 0) * NTHR]);
            f32x4 b = __builtin_nontemporal_load(&x4[base + (g * 4 + 1) * NTHR]);
            f32x4 c = __builtin_nontemporal_load(&x4[base + (g * 4 + 2) * NTHR]);
            f32x4 d = __builtin_nontemporal_load(&x4[base + (g * 4 + 3) * NTHR]);
            s0 += a[0] + a[1] + a[2] + a[3];
            s1 += b[0] + b[1] + b[2] + b[3];
            s2 += c[0] + c[1] + c[2] + c[3];
            s3 += d[0] + d[1] + d[2] + d[3];
            q0 = fmaf(a[0], a[0], q0); q0 = fmaf(a[1], a[1], q0);
            q0 = fmaf(a[2], a[2], q0); q0 = fmaf(a[3], a[3], q0);
            q1 = fmaf(b[0], b[0], q1); q1 = fmaf(b[1], b[1], q1);
            q1 = fmaf(b[2], b[2], q1); q1 = fmaf(b[3], b[3], q1);
            q2 = fmaf(c[0], c[0], q2); q2 = fmaf(c[1], c[1], q2);
            q2 = fmaf(c[2], c[2], q2); q2 = fmaf(c[3], c[3], q2);
            q3 = fmaf(d[0], d[0], q3); q3 = fmaf(d[1], d[1], q3);
            q3 = fmaf(d[2], d[2], q3); q3 = fmaf(d[3], d[3], q3);
        }
    } else {
        // Generic grid-stride fallback.
        const int tid = blockIdx.x * NTHR + threadIdx.x;
        const int stride = NBLK * NTHR;
        for (int i = tid; i < n4; i += stride) {
            f32x4 a = __builtin_nontemporal_load(&x4[i]);
            s0 += a[0] + a[1] + a[2] + a[3];
            q0 = fmaf(a[0], a[0], q0); q0 = fmaf(a[1], a[1], q0);
            q0 = fmaf(a[2], a[2], q0); q0 = fmaf(a[3], a[3], q0);
        }
    }
    float s = (s0 + s1) + (s2 + s3);
    float q = (q0 + q1) + (q2 + q3);

    #pragma unroll
    for (int off = 32; off > 0; off >>= 1) {
        s += __shfl_down(s, off, 64);
        q += __shfl_down(q, off, 64);
    }

    __shared__ float2 lds[NWAVE];
    const int lane = threadIdx.x & 63;
    const int wave = threadIdx.x >> 6;
    if (lane == 0) lds[wave] = make_float2(s, q);
    __syncthreads();

    if (threadIdx.x == 0) {
        float2 acc = lds[0];
        #pragma unroll
        for (int w = 1; w < NWAVE; ++w) {
            acc.x += lds[w].x;
            acc.y += lds[w].y;
        }
        part[blockIdx.x] = acc;
    }
}

// Kernel 2: single wave. Partials read as float4 (pairs of float2).
__global__ __launch_bounds__(64) void grt_final_kernel(
    const float4* __restrict__ part4,  // NBLK/2 float4
    const float* __restrict__ log_sw, const float* __restrict__ log_sz,
    const float* __restrict__ log_sx, float* __restrict__ out, float dn) {
    float s = 0.f, q = 0.f;
    #pragma unroll 4
    for (int i = threadIdx.x; i < NBLK / 2; i += 64) {
        float4 v = part4[i];
        s += v.x + v.z;
        q += v.y + v.w;
    }

    #pragma unroll
    for (int off = 32; off > 0; off >>= 1) {
        s += __shfl_down(s, off, 64);
        q += __shfl_down(q, off, 64);
    }

    if (threadIdx.x == 0) {
        double ss = (double)s, qq = (double)q;
        double n = (double)dn;
        double b = exp(2.0 * (double)log_sw[0]);
        double a = exp(2.0 * (double)log_sz[0]) + exp(2.0 * (double)log_sx[0]);
        double quad = qq / a - b * ss * ss / (a * (a + n * b));
        double logdet = (n - 1.0) * log(a) + log(a + n * b);
        const double LOG_2PI = 1.837877066409345483560659472811;
        out[0] = (float)(-0.5 * (n * LOG_2PI + logdet + quad));
    }
}

extern "C" void kernel_launch(void* const* d_in, const int* in_sizes, int n_in,
                              void* d_out, int out_size, void* d_ws, size_t ws_size,
                              hipStream_t stream) {
    const float* x      = (const float*)d_in[0];
    const float* log_sw = (const float*)d_in[1];
    const float* log_sz = (const float*)d_in[2];
    const float* log_sx = (const float*)d_in[3];
    float* out = (float*)d_out;
    int n = in_sizes[0];  // 33554432
    int n4 = n >> 2;

    float2* part = (float2*)d_ws;  // 2048 float2 = 16 KiB

    grt_partial_kernel<<<NBLK, NTHR, 0, stream>>>(x, part, n4);
    grt_final_kernel<<<1, 64, 0, stream>>>((const float4*)part, log_sw, log_sz,
                                           log_sx, out, (float)n);
}